// Round 3
// baseline (652.076 us; speedup 1.0000x reference)
//
#include <hip/hip_runtime.h>

// DIAGNOSTIC ROUND: identical compute kernel to R1, launched TWICE.
// Purpose: dur_us(delta vs R1) = duration of the second dispatch, which
// discriminates compute-bound (~+170us, cache-insensitive) from
// memory-bound-near-roofline (~+40..80us, 2nd pass partially LLC-resident).
// Kernel is idempotent (every out element rewritten), so double-launch is safe.

#define NCHUNK    102400
#define GRID_DIM  2048
#define BLOCK_DIM 256

#define FADD_DPP(acc, ctrl, rmask)                                             \
  do {                                                                         \
    int _t = __builtin_amdgcn_update_dpp(0, __float_as_int(acc), (ctrl),       \
                                         (rmask), 0xF, true);                  \
    (acc) += __int_as_float(_t);                                               \
  } while (0)

#define HALF_REDUCE3(a0, a1, a2)                                               \
  do {                                                                         \
    FADD_DPP(a0, 0x111, 0xF); FADD_DPP(a1, 0x111, 0xF); FADD_DPP(a2, 0x111, 0xF); \
    FADD_DPP(a0, 0x112, 0xF); FADD_DPP(a1, 0x112, 0xF); FADD_DPP(a2, 0x112, 0xF); \
    FADD_DPP(a0, 0x114, 0xF); FADD_DPP(a1, 0x114, 0xF); FADD_DPP(a2, 0x114, 0xF); \
    FADD_DPP(a0, 0x118, 0xF); FADD_DPP(a1, 0x118, 0xF); FADD_DPP(a2, 0x118, 0xF); \
    FADD_DPP(a0, 0x142, 0xA); FADD_DPP(a1, 0x142, 0xA); FADD_DPP(a2, 0x142, 0xA); \
  } while (0)

__global__ __launch_bounds__(BLOCK_DIM, 8)
void mlp_rsna9_kernel(const float* __restrict__ x,
                      const float* __restrict__ Wsp, const float* __restrict__ bsp,
                      const float* __restrict__ Wnf, const float* __restrict__ bnf,
                      const float* __restrict__ Wss, const float* __restrict__ bss,
                      float* __restrict__ out)
{
    __shared__ __align__(16) float w_lds[3 * 3 * 128];
    __shared__ float b_lds[12];

    const int tid = threadIdx.x;

    for (int idx = tid; idx < 1152; idx += BLOCK_DIM) {
        int t = idx / 384;
        int r = idx - t * 384;
        int c = r >> 7;
        int i = r & 127;
        const float* wp = (t == 0) ? Wsp : (t == 1) ? Wnf : Wss;
        w_lds[idx] = wp[i * 3 + c];
    }
    if (tid < 9) {
        int t = tid / 3;
        int c = tid - t * 3;
        const float* bp = (t == 0) ? bsp : (t == 1) ? bnf : bss;
        b_lds[tid] = bp[c];
    }
    __syncthreads();

    const int half = tid >> 5;
    const int i0   = (tid & 31) << 2;

    for (int base = blockIdx.x * 2; base < NCHUNK; base += GRID_DIM * 2) {
        const int c0 = base, c1 = base + 1;

        const float4 xv0 = *(const float4*)(x + (size_t)c0 * 1024 + (size_t)tid * 4);
        const float4 xv1 = *(const float4*)(x + (size_t)c1 * 1024 + (size_t)tid * 4);

        const int seg0 = c0 * 8 + half;
        const int seg1 = c1 * 8 + half;
        const int g0 = seg0 % 25;
        const int g1 = seg1 % 25;
        const int t0 = (g0 >= 5) + (g0 >= 15);
        const int t1 = (g1 >= 5) + (g1 >= 15);

        const float* wb0 = w_lds + t0 * 384 + i0;
        const float4 w00 = *(const float4*)(wb0);
        const float4 w01 = *(const float4*)(wb0 + 128);
        const float4 w02 = *(const float4*)(wb0 + 256);
        const float* wb1 = w_lds + t1 * 384 + i0;
        const float4 w10 = *(const float4*)(wb1);
        const float4 w11 = *(const float4*)(wb1 + 128);
        const float4 w12 = *(const float4*)(wb1 + 256);

        float a00 = xv0.x * w00.x + xv0.y * w00.y + xv0.z * w00.z + xv0.w * w00.w;
        float a01 = xv0.x * w01.x + xv0.y * w01.y + xv0.z * w01.z + xv0.w * w01.w;
        float a02 = xv0.x * w02.x + xv0.y * w02.y + xv0.z * w02.z + xv0.w * w02.w;
        float a10 = xv1.x * w10.x + xv1.y * w10.y + xv1.z * w10.z + xv1.w * w10.w;
        float a11 = xv1.x * w11.x + xv1.y * w11.y + xv1.z * w11.z + xv1.w * w11.w;
        float a12 = xv1.x * w12.x + xv1.y * w12.y + xv1.z * w12.z + xv1.w * w12.w;

        HALF_REDUCE3(a00, a01, a02);
        HALF_REDUCE3(a10, a11, a12);

        if ((tid & 31) == 31) {
            float* op0 = out + (size_t)seg0 * 3;
            op0[0] = a00 + b_lds[t0 * 3 + 0];
            op0[1] = a01 + b_lds[t0 * 3 + 1];
            op0[2] = a02 + b_lds[t0 * 3 + 2];
            float* op1 = out + (size_t)seg1 * 3;
            op1[0] = a10 + b_lds[t1 * 3 + 0];
            op1[1] = a11 + b_lds[t1 * 3 + 1];
            op1[2] = a12 + b_lds[t1 * 3 + 2];
        }
    }
}

extern "C" void kernel_launch(void* const* d_in, const int* in_sizes, int n_in,
                              void* d_out, int out_size, void* d_ws, size_t ws_size,
                              hipStream_t stream)
{
    const float* x   = (const float*)d_in[0];
    const float* Wsp = (const float*)d_in[3];
    const float* bsp = (const float*)d_in[4];
    const float* Wnf = (const float*)d_in[5];
    const float* bnf = (const float*)d_in[6];
    const float* Wss = (const float*)d_in[7];
    const float* bss = (const float*)d_in[8];
    float* out = (float*)d_out;

    // Two identical launches (diagnostic): delta vs single-launch dur_us
    // isolates one full kernel dispatch's duration.
    for (int rep = 0; rep < 2; ++rep) {
        mlp_rsna9_kernel<<<GRID_DIM, BLOCK_DIM, 0, stream>>>(
            x, Wsp, bsp, Wnf, bnf, Wss, bss, out);
    }
}

// Round 4
// 567.486 us; speedup vs baseline: 1.1491x; 1.1491x over previous
//
#include <hip/hip_runtime.h>

// B=32768, G=25, IN=128, NC=3, OUT=75. K/V are arange -> identity fold.
// seg s = b*25+g covers x[s*128..+127]; out[s*3+c] = dot(seg, W_t[:,c]) + b_t[c],
// t = (g>=5)+(g>=15). Chunk = 1024 floats = 8 segments. NCHUNK = 102400.
//
// R3 design: contiguous per-block partition (block b owns 50 chunks = 50 KB),
// software-pipelined prefetch (next iter's 2 float4 in flight before consuming
// current -> 4 outstanding loads/wave), incremental g (no % in loop), DPP
// half-wave reduction (VALU pipe only). Kernel measured ~91us via R2
// double-launch delta; target ~70us (419 MB @ 6.3 TB/s read ceiling).

#define BLOCK_DIM 256
#define GRID_DIM  2048      // 102400 chunks / 50 per block
#define CPB       50        // chunks per block
#define ITERS     25        // 2 chunks per iteration

#define FADD_DPP(acc, ctrl, rmask)                                             \
  do {                                                                         \
    int _t = __builtin_amdgcn_update_dpp(0, __float_as_int(acc), (ctrl),       \
                                         (rmask), 0xF, true);                  \
    (acc) += __int_as_float(_t);                                               \
  } while (0)

// Sum 3 accumulators across each 32-lane half; result in lanes 31 / 63.
#define HALF_REDUCE3(a0, a1, a2)                                               \
  do {                                                                         \
    FADD_DPP(a0, 0x111, 0xF); FADD_DPP(a1, 0x111, 0xF); FADD_DPP(a2, 0x111, 0xF); \
    FADD_DPP(a0, 0x112, 0xF); FADD_DPP(a1, 0x112, 0xF); FADD_DPP(a2, 0x112, 0xF); \
    FADD_DPP(a0, 0x114, 0xF); FADD_DPP(a1, 0x114, 0xF); FADD_DPP(a2, 0x114, 0xF); \
    FADD_DPP(a0, 0x118, 0xF); FADD_DPP(a1, 0x118, 0xF); FADD_DPP(a2, 0x118, 0xF); \
    FADD_DPP(a0, 0x142, 0xA); FADD_DPP(a1, 0x142, 0xA); FADD_DPP(a2, 0x142, 0xA); \
  } while (0)

__global__ __launch_bounds__(BLOCK_DIM, 8)
void mlp_rsna9_kernel(const float* __restrict__ x,
                      const float* __restrict__ Wsp, const float* __restrict__ bsp,
                      const float* __restrict__ Wnf, const float* __restrict__ bnf,
                      const float* __restrict__ Wss, const float* __restrict__ bss,
                      float* __restrict__ out)
{
    // w_lds[t*384 + c*128 + i] = W_t[i*3 + c]
    __shared__ __align__(16) float w_lds[3 * 3 * 128];
    __shared__ float b_lds[12];

    const int tid = threadIdx.x;

    for (int idx = tid; idx < 1152; idx += BLOCK_DIM) {
        int t = idx / 384;
        int r = idx - t * 384;
        int c = r >> 7;
        int i = r & 127;
        const float* wp = (t == 0) ? Wsp : (t == 1) ? Wnf : Wss;
        w_lds[idx] = wp[i * 3 + c];
    }
    if (tid < 9) {
        int t = tid / 3;
        int c = tid - t * 3;
        const float* bp = (t == 0) ? bsp : (t == 1) ? bnf : bss;
        b_lds[tid] = bp[c];
    }
    __syncthreads();

    const int half = tid >> 5;          // segment slot within a chunk (0..7)
    const int i0   = (tid & 31) << 2;   // element offset within 128-float segment

    const int c0 = blockIdx.x * CPB;    // first chunk owned by this block
    int g0 = (c0 * 8 + half) % 25;      // group of chunk-A segment (once; wrap in loop)

    const float* xp = x + (size_t)c0 * 1024 + (size_t)tid * 4;
    float*       op = out + ((size_t)c0 * 8 + half) * 3;

    // Prime the pipeline: chunk pair (c0, c0+1)
    float4 pA = *(const float4*)(xp);
    float4 pB = *(const float4*)(xp + 1024);

    for (int j = 0; j < ITERS; ++j) {
        // Prefetch next chunk pair (clamped to current on last iter: L1/L2-hot, in-bounds)
        const float* xn = xp + ((j < ITERS - 1) ? 2048 : 0);
        float4 nA = *(const float4*)(xn);
        float4 nB = *(const float4*)(xn + 1024);

        int g1 = g0 + 8; if (g1 >= 25) g1 -= 25;
        const int t0 = (g0 >= 5) + (g0 >= 15);
        const int t1 = (g1 >= 5) + (g1 >= 15);

        const float* wb0 = w_lds + t0 * 384 + i0;
        const float4 w00 = *(const float4*)(wb0);
        const float4 w01 = *(const float4*)(wb0 + 128);
        const float4 w02 = *(const float4*)(wb0 + 256);
        const float* wb1 = w_lds + t1 * 384 + i0;
        const float4 w10 = *(const float4*)(wb1);
        const float4 w11 = *(const float4*)(wb1 + 128);
        const float4 w12 = *(const float4*)(wb1 + 256);

        float a00 = pA.x * w00.x + pA.y * w00.y + pA.z * w00.z + pA.w * w00.w;
        float a01 = pA.x * w01.x + pA.y * w01.y + pA.z * w01.z + pA.w * w01.w;
        float a02 = pA.x * w02.x + pA.y * w02.y + pA.z * w02.z + pA.w * w02.w;
        float a10 = pB.x * w10.x + pB.y * w10.y + pB.z * w10.z + pB.w * w10.w;
        float a11 = pB.x * w11.x + pB.y * w11.y + pB.z * w11.z + pB.w * w11.w;
        float a12 = pB.x * w12.x + pB.y * w12.y + pB.z * w12.z + pB.w * w12.w;

        HALF_REDUCE3(a00, a01, a02);
        HALF_REDUCE3(a10, a11, a12);

        if ((tid & 31) == 31) {
            op[0] = a00 + b_lds[t0 * 3 + 0];   // segment c*8+half
            op[1] = a01 + b_lds[t0 * 3 + 1];
            op[2] = a02 + b_lds[t0 * 3 + 2];
            op[24] = a10 + b_lds[t1 * 3 + 0];  // segment (c+1)*8+half = +8 segs = +24 floats
            op[25] = a11 + b_lds[t1 * 3 + 1];
            op[26] = a12 + b_lds[t1 * 3 + 2];
        }

        pA = nA; pB = nB;
        xp += 2048;
        op += 48;                        // 16 segments * 3 floats per iteration
        g0 += 16; if (g0 >= 25) g0 -= 25;
    }
}

extern "C" void kernel_launch(void* const* d_in, const int* in_sizes, int n_in,
                              void* d_out, int out_size, void* d_ws, size_t ws_size,
                              hipStream_t stream)
{
    const float* x   = (const float*)d_in[0];
    const float* Wsp = (const float*)d_in[3];
    const float* bsp = (const float*)d_in[4];
    const float* Wnf = (const float*)d_in[5];
    const float* bnf = (const float*)d_in[6];
    const float* Wss = (const float*)d_in[7];
    const float* bss = (const float*)d_in[8];
    float* out = (float*)d_out;

    mlp_rsna9_kernel<<<GRID_DIM, BLOCK_DIM, 0, stream>>>(
        x, Wsp, bsp, Wnf, bnf, Wss, bss, out);
}